// Round 9
// baseline (796.638 us; speedup 1.0000x reference)
//
#include <hip/hip_runtime.h>
#include <math.h>

#define B_SZ 1024
#define T_SZ 512
#define C_CH 65
#define HID  160
#define OUTD 32
#define M_ELEM 8
#define NBLK 128          // B_SZ / M_ELEM
#define NTHR 640          // 10 waves
#define HPAD 168          // padded bf16 row stride (336B: stride walks all banks)

#define LOG2E 1.4426950408889634f

// workspace layout (bytes)
#define OBS_OFF 0                    // 1024*512 = 512KB
#define ANY_OFF  524288              // 2KB
#define XD0_OFF  526336              // 1024*512*4 = 2MB
#define S_OFF    2623488             // 512*1024*8 = 4MB
#define WHH_OFF  6817792             // 153600B
#define WIH_OFF  6971392             // 30720B  (total ~7.0MB)

typedef float f32x4_t __attribute__((ext_vector_type(4)));
typedef short bf16x8_t __attribute__((ext_vector_type(8)));

__device__ __forceinline__ unsigned short f2bf(float x) {
  unsigned int u = __float_as_uint(x);
  unsigned int r = ((u >> 16) & 1u) + 0x7FFFu;
  return (unsigned short)((u + r) >> 16);
}
__device__ __forceinline__ unsigned cvt_pk_bf16(float lo, float hi) {
  unsigned r;
  asm("v_cvt_pk_bf16_f32 %0, %1, %2" : "=v"(r) : "v"(lo), "v"(hi));
  return r;
}
__device__ __forceinline__ float exp2_f(float x) {
  float r; asm("v_exp_f32 %0, %1" : "=v"(r) : "v"(x)); return r;
}
__device__ __forceinline__ float rcp_f(float x) {
  float r; asm("v_rcp_f32 %0, %1" : "=v"(r) : "v"(x)); return r;
}

// ---------------- phase 0: zero any-flags ----------------
__global__ void k_zero(unsigned* __restrict__ anyv) {
  int i = blockIdx.x * blockDim.x + threadIdx.x;
  if (i < T_SZ) anyv[i] = 0u;
}

// ---------------- phase 1: obs + any + Xd0 ----------------
__global__ __launch_bounds__(256) void k_prep(const float* __restrict__ X,
                                              const float* __restrict__ times,
                                              unsigned char* __restrict__ obs,
                                              unsigned* __restrict__ anyv,
                                              float* __restrict__ xd0) {
  const int b = blockIdx.x;
  const float* Xb = X + (size_t)b * T_SZ * C_CH;
  for (int t = threadIdx.x; t < T_SZ; t += 256) {
    const float* cur = Xb + t * C_CH;
    const float* prv = cur - C_CH;
    float m = -1e30f;
    if (t == 0) {
      #pragma unroll
      for (int c = 1; c <= 32; ++c) m = fmaxf(m, cur[c]);
    } else {
      #pragma unroll
      for (int c = 1; c <= 32; ++c) m = fmaxf(m, cur[c] - prv[c]);
    }
    unsigned char o = (m > 0.5f) ? (unsigned char)1 : (unsigned char)0;
    obs[(size_t)b * T_SZ + t] = o;
    if (o) atomicOr(&anyv[t], 1u);
    xd0[(size_t)b * T_SZ + t] = cur[0] - times[(t == 0) ? 0 : (t - 1)];
  }
}

// ---------------- phase 1b: per-element dt prefix + flag table -----------
// S[t][b] = {dt_used(b,t), flag = any && obs && t<=fi}
__global__ __launch_bounds__(256) void k_dt(const unsigned char* __restrict__ obs,
                                            const unsigned* __restrict__ anyv,
                                            const float* __restrict__ xd0,
                                            const int* __restrict__ fidx,
                                            float2* __restrict__ S) {
  const int b = blockIdx.x * 256 + threadIdx.x;     // 4 blocks x 256
  const unsigned char* ob = obs + (size_t)b * T_SZ;
  const float* xd = xd0 + (size_t)b * T_SZ;
  const int fi = fidx[b];
  float dt = 0.f;
  for (int t = 0; t < T_SZ; ++t) {
    const int any = (int)anyv[t];
    const int o = (int)ob[t];
    const float flag = (any && o && t <= fi) ? 1.f : 0.f;
    S[(size_t)t * B_SZ + b] = make_float2(dt, flag);
    if (any && !o) dt += xd[t];
  }
}

// ---------------- phase 1c: pack PRESCALED weights into bf16 B-frags -----
// gates r,z scaled by -log2e; gate n (ih and hh) scaled by -2*log2e, so the
// in-loop activations become rcp(1+exp2(v)) and a rational tanh.
__global__ __launch_bounds__(256) void k_pack(const float* __restrict__ w_ih,
                                              const float* __restrict__ w_hh,
                                              unsigned short* __restrict__ whh_f,
                                              unsigned short* __restrict__ wih_f) {
  int i = blockIdx.x * 256 + threadIdx.x;
  if (i < 9600) {
    int l = i & 63; int kt = (i >> 6) % 5; int g = (i / 320) % 3; int q = i / 960;
    const float scl = (g < 2) ? -LOG2E : -2.f * LOG2E;
    int row = g * 160 + q * 16 + (l & 15);
    const float* src = w_hh + (size_t)row * HID + kt * 32 + (l >> 4) * 8;
    unsigned short* dst = whh_f + (size_t)i * 8;
    #pragma unroll
    for (int j = 0; j < 8; ++j) dst[j] = f2bf(scl * src[j]);
  } else if (i < 11520) {
    int i2 = i - 9600;
    int l = i2 & 63; int g = (i2 >> 6) % 3; int q = i2 / 192;
    const float scl = (g < 2) ? -LOG2E : -2.f * LOG2E;
    int row = g * 160 + q * 16 + (l & 15);
    const float* src = w_ih + (size_t)row * 32 + (l >> 4) * 8;
    unsigned short* dst = wih_f + (size_t)i2 * 8;
    #pragma unroll
    for (int j = 0; j < 8; ++j) dst[j] = f2bf(scl * src[j]);
  }
}

#define MFMA16 __builtin_amdgcn_mfma_f32_16x16x32_bf16

// ---------------- phase 2: batched MFMA recurrence ------------------------
// 8 elements/block, 10 waves; wave q owns 16 gate-cols x 3 gates.
// A-frag rows 8-15 hold elements {2,3,0,1,6,7,4,5} so every lane's two
// combine rows are ALWAYS acc regs {0,1} (no row-select cndmask).
// ih MFMAs for step t+1 are issued at the end of step t (gin carry).
// dt/obs/any/alive all folded into the precomputed S table.
__global__ __launch_bounds__(NTHR) void k_scan(
    const float* __restrict__ X, const int* __restrict__ fidx,
    const float* __restrict__ w_ih,
    const float* __restrict__ b_ih, const float* __restrict__ b_hh,
    const float* __restrict__ lin_w, const float* __restrict__ lin_b,
    const float2* __restrict__ Sf,
    const unsigned short* __restrict__ whh_f, const unsigned short* __restrict__ wih_f,
    float* __restrict__ out)
{
  const int b0 = blockIdx.x * M_ELEM;
  const int tid = threadIdx.x;
  const int wid = tid >> 6;
  const int lane = tid & 63;
  const int q = wid;

  __shared__ __align__(16) unsigned short hrow[2][M_ELEM][HPAD]; // bf16 h dbuf
  __shared__ __align__(16) float hm[M_ELEM][HID];

  { unsigned int* hz = (unsigned int*)hrow;
    for (int i = tid; i < 2 * M_ELEM * HPAD / 2; i += NTHR) hz[i] = 0u; }

  int maxfi = 0;
  #pragma unroll
  for (int e = 0; e < M_ELEM; ++e) maxfi = max(maxfi, fidx[b0 + e]);

  // A-frag row -> element map (rows 8-15 permuted duplicates)
  const int r16 = lane & 15;
  const int elA = (r16 < 8) ? r16 : ((r16 & 4) | ((r16 & 3) ^ 2));
  // combine rows: always acc regs {0,1}; group g=lane>>4 -> rows {0,1},{4,5},{2,3},{6,7}
  const int mA = ((lane >> 4) & 1) * 4 + ((lane >> 5) & 1) * 2;
  const int mB = mA + 1;

  // ---- resident weight fragments ----
  bf16x8_t whh_v[3][5];
  bf16x8_t wih_v[3];
  #pragma unroll
  for (int g = 0; g < 3; ++g) {
    #pragma unroll
    for (int kt = 0; kt < 5; ++kt)
      whh_v[g][kt] = *(const bf16x8_t*)(whh_f + ((size_t)((q * 3 + g) * 5 + kt) * 64 + lane) * 8);
    wih_v[g] = *(const bf16x8_t*)(wih_f + ((size_t)(q * 3 + g) * 64 + lane) * 8);
  }
  const int col = q * 16 + (lane & 15);
  const float b_r  = -LOG2E * (b_ih[col] + b_hh[col]);
  const float b_z  = -LOG2E * (b_ih[160 + col] + b_hh[160 + col]);
  const float b_ni = -2.f * LOG2E * b_ih[320 + col];
  const float b_nh = -2.f * LOG2E * b_hh[320 + col];
  const float w0r = -LOG2E * w_ih[(size_t)col * 32];
  const float w0z = -LOG2E * w_ih[(size_t)(160 + col) * 32];
  const float w0n = -2.f * LOG2E * w_ih[(size_t)(320 + col) * 32];

  float hA = 0.f, hB = 0.f;
  const f32x4_t z4 = {0.f, 0.f, 0.f, 0.f};

  const float* xrow_base =
      X + ((size_t)(b0 + elA) * T_SZ) * C_CH + 33 + ((lane >> 4) * 8);

  // ---- prologue: gin for t=0, S for t=0 ----
  f32x4_t ginr, ginz, ginn;
  {
    float x0[8];
    #pragma unroll
    for (int j = 0; j < 8; ++j) x0[j] = xrow_base[j];
    bf16x8_t xf; unsigned* xfu = (unsigned*)&xf;
    #pragma unroll
    for (int j = 0; j < 4; ++j) xfu[j] = cvt_pk_bf16(x0[2 * j], x0[2 * j + 1]);
    ginr = MFMA16(xf, wih_v[0], z4, 0, 0, 0);
    ginz = MFMA16(xf, wih_v[1], z4, 0, 0, 0);
    ginn = MFMA16(xf, wih_v[2], z4, 0, 0, 0);
  }
  float2 sA = Sf[b0 + mA];
  float2 sB = Sf[b0 + mB];
  __syncthreads();

  // ---- the recurrence ----
  for (int t = 0; t <= maxfi; ++t) {
    const int p = t & 1, pn = p ^ 1;
    const int tn = (t < maxfi) ? (t + 1) : maxfi;

    // A. prefetch t+1 (x row + S entries)
    float xn[8];
    const float* xr = xrow_base + (size_t)tn * C_CH;
    #pragma unroll
    for (int j = 0; j < 8; ++j) xn[j] = xr[j];
    const float2 sAn = Sf[(size_t)tn * B_SZ + b0 + mA];
    const float2 sBn = Sf[(size_t)tn * B_SZ + b0 + mB];

    // B. h A-frags (bank-permuted padded rows; dup lanes broadcast)
    bf16x8_t hf0, hf1, hf2, hf3, hf4;
    {
      const unsigned short* hp = &hrow[p][elA][(lane >> 4) * 8];
      hf0 = *(const bf16x8_t*)(hp);
      hf1 = *(const bf16x8_t*)(hp + 32);
      hf2 = *(const bf16x8_t*)(hp + 64);
      hf3 = *(const bf16x8_t*)(hp + 96);
      hf4 = *(const bf16x8_t*)(hp + 128);
    }

    // C. 15 hh MFMAs, gin as C-input, 6 parallel chains
    __builtin_amdgcn_s_setprio(1);
    f32x4_t ra  = MFMA16(hf0, whh_v[0][0], ginr, 0, 0, 0);
    f32x4_t za  = MFMA16(hf0, whh_v[1][0], ginz, 0, 0, 0);
    f32x4_t nha = MFMA16(hf0, whh_v[2][0], z4,   0, 0, 0);
    f32x4_t rb  = MFMA16(hf2, whh_v[0][2], z4,   0, 0, 0);
    f32x4_t zb  = MFMA16(hf2, whh_v[1][2], z4,   0, 0, 0);
    f32x4_t nhb = MFMA16(hf3, whh_v[2][3], z4,   0, 0, 0);
    ra  = MFMA16(hf1, whh_v[0][1], ra,  0, 0, 0);
    za  = MFMA16(hf1, whh_v[1][1], za,  0, 0, 0);
    nha = MFMA16(hf1, whh_v[2][1], nha, 0, 0, 0);
    rb  = MFMA16(hf3, whh_v[0][3], rb,  0, 0, 0);
    zb  = MFMA16(hf3, whh_v[1][3], zb,  0, 0, 0);
    nhb = MFMA16(hf4, whh_v[2][4], nhb, 0, 0, 0);
    nha = MFMA16(hf2, whh_v[2][2], nha, 0, 0, 0);
    rb  = MFMA16(hf4, whh_v[0][4], rb,  0, 0, 0);
    zb  = MFMA16(hf4, whh_v[1][4], zb,  0, 0, 0);
    __builtin_amdgcn_s_setprio(0);

    const f32x4_t accr  = ra + rb;
    const f32x4_t accz  = za + zb;
    const f32x4_t accnh = nha + nhb;

    // D. combine: 2 rows per lane, regs {0,1} always; prescaled activations
    {
      const float pre_r = accr[0] + fmaf(sA.x, w0r, b_r);
      const float rr = rcp_f(1.f + exp2_f(pre_r));
      const float pre_z = accz[0] + fmaf(sA.x, w0z, b_z);
      const float zz = rcp_f(1.f + exp2_f(pre_z));
      const float u = (ginn[0] + fmaf(sA.x, w0n, b_ni)) + rr * (accnh[0] + b_nh);
      const float e = exp2_f(fminf(u, 60.f));
      const float nn = (1.f - e) * rcp_f(1.f + e);
      const float upd = nn + zz * (hA - nn);
      hA = (sA.y != 0.f) ? upd : hA;
    }
    {
      const float pre_r = accr[1] + fmaf(sB.x, w0r, b_r);
      const float rr = rcp_f(1.f + exp2_f(pre_r));
      const float pre_z = accz[1] + fmaf(sB.x, w0z, b_z);
      const float zz = rcp_f(1.f + exp2_f(pre_z));
      const float u = (ginn[1] + fmaf(sB.x, w0n, b_ni)) + rr * (accnh[1] + b_nh);
      const float e = exp2_f(fminf(u, 60.f));
      const float nn = (1.f - e) * rcp_f(1.f + e);
      const float upd = nn + zz * (hB - nn);
      hB = (sB.y != 0.f) ? upd : hB;
    }

    // E. publish h (2x ds_write_b16 into bank-permuted rows)
    {
      const unsigned hw = cvt_pk_bf16(hA, hB);
      hrow[pn][mA][col] = (unsigned short)hw;
      hrow[pn][mB][col] = (unsigned short)(hw >> 16);
    }

    // F. gin for t+1 (ih MFMAs hoisted out of next step's critical chain)
    {
      bf16x8_t xf; unsigned* xfu = (unsigned*)&xf;
      #pragma unroll
      for (int j = 0; j < 4; ++j) xfu[j] = cvt_pk_bf16(xn[2 * j], xn[2 * j + 1]);
      ginr = MFMA16(xf, wih_v[0], z4, 0, 0, 0);
      ginz = MFMA16(xf, wih_v[1], z4, 0, 0, 0);
      ginn = MFMA16(xf, wih_v[2], z4, 0, 0, 0);
    }
    sA = sAn; sB = sBn;
    __syncthreads();
  }

  // ---- epilogue: h -> LDS, then out = lin_w @ h + lin_b ----
  hm[mA][col] = hA;
  hm[mB][col] = hB;
  __syncthreads();
  if (tid < 256) {
    const int e = tid >> 5, o = tid & 31;
    const float4* lw = (const float4*)(lin_w + o * HID);
    const float4* hv = (const float4*)(&hm[e][0]);
    float a0 = 0.f, a1 = 0.f, a2 = 0.f, a3 = 0.f;
    #pragma unroll
    for (int k = 0; k < HID / 4; ++k) {
      float4 w = lw[k], h = hv[k];
      a0 = fmaf(w.x, h.x, a0); a1 = fmaf(w.y, h.y, a1);
      a2 = fmaf(w.z, h.z, a2); a3 = fmaf(w.w, h.w, a3);
    }
    out[(size_t)(b0 + e) * OUTD + o] = lin_b[o] + (a0 + a1) + (a2 + a3);
  }
}

extern "C" void kernel_launch(void* const* d_in, const int* in_sizes, int n_in,
                              void* d_out, int out_size, void* d_ws, size_t ws_size,
                              hipStream_t stream) {
  const float* times = (const float*)d_in[0];
  const float* X     = (const float*)d_in[1];
  const int*   fidx  = (const int*)d_in[2];
  const float* w_ih  = (const float*)d_in[3];
  const float* w_hh  = (const float*)d_in[4];
  const float* b_ih  = (const float*)d_in[5];
  const float* b_hh  = (const float*)d_in[6];
  const float* lin_w = (const float*)d_in[7];
  const float* lin_b = (const float*)d_in[8];
  float* outp = (float*)d_out;

  unsigned char* obsb = (unsigned char*)d_ws + OBS_OFF;
  unsigned* anyv = (unsigned*)((char*)d_ws + ANY_OFF);
  float* xd0 = (float*)((char*)d_ws + XD0_OFF);
  float2* S = (float2*)((char*)d_ws + S_OFF);
  unsigned short* whh_f = (unsigned short*)((char*)d_ws + WHH_OFF);
  unsigned short* wih_f = (unsigned short*)((char*)d_ws + WIH_OFF);

  k_zero<<<1, 512, 0, stream>>>(anyv);
  k_prep<<<B_SZ, 256, 0, stream>>>(X, times, obsb, anyv, xd0);
  k_dt<<<B_SZ / 256, 256, 0, stream>>>(obsb, anyv, xd0, fidx, S);
  k_pack<<<45, 256, 0, stream>>>(w_ih, w_hh, whh_f, wih_f);
  k_scan<<<NBLK, NTHR, 0, stream>>>(X, fidx, w_ih, b_ih, b_hh,
                                    lin_w, lin_b, S, whh_f, wih_f, outp);
}

// Round 10
// 573.824 us; speedup vs baseline: 1.3883x; 1.3883x over previous
//
#include <hip/hip_runtime.h>
#include <math.h>

#define B_SZ 1024
#define T_SZ 512
#define C_CH 65
#define HID  160
#define OUTD 32
#define M_ELEM 8
#define NBLK 128          // B_SZ / M_ELEM
#define NTHR 640          // 10 waves
#define HPAD 168          // padded bf16 row stride (336B: stride walks all banks)

#define LOG2E 1.4426950408889634f

// workspace layout (bytes)
#define OBS_OFF 0                    // 1024*512 = 512KB
#define ANY_OFF  524288              // 2KB
#define XD0_OFF  526336              // 1024*512*4 = 2MB
#define S_OFF    2623488             // 512*1024*8 = 4MB
#define WHH_OFF  6817792             // 153600B
#define WIH_OFF  6971392             // 30720B  (total ~7.0MB)

typedef float f32x4_t __attribute__((ext_vector_type(4)));
typedef float f32x2_t __attribute__((ext_vector_type(2)));
typedef short bf16x8_t __attribute__((ext_vector_type(8)));

__device__ __forceinline__ unsigned short f2bf(float x) {
  unsigned int u = __float_as_uint(x);
  unsigned int r = ((u >> 16) & 1u) + 0x7FFFu;
  return (unsigned short)((u + r) >> 16);
}
__device__ __forceinline__ unsigned cvt_pk_bf16(float lo, float hi) {
  unsigned r;
  asm("v_cvt_pk_bf16_f32 %0, %1, %2" : "=v"(r) : "v"(lo), "v"(hi));
  return r;
}
__device__ __forceinline__ float exp2_f(float x) {
  float r; asm("v_exp_f32 %0, %1" : "=v"(r) : "v"(x)); return r;
}
__device__ __forceinline__ float rcp_f(float x) {
  float r; asm("v_rcp_f32 %0, %1" : "=v"(r) : "v"(x)); return r;
}
__device__ __forceinline__ f32x2_t lo2(f32x4_t v) {
  return __builtin_shufflevector(v, v, 0, 1);
}

// ---------------- phase 0: zero any-flags ----------------
__global__ void k_zero(unsigned* __restrict__ anyv) {
  int i = blockIdx.x * blockDim.x + threadIdx.x;
  if (i < T_SZ) anyv[i] = 0u;
}

// ---------------- phase 1: obs + any + Xd0 ----------------
__global__ __launch_bounds__(256) void k_prep(const float* __restrict__ X,
                                              const float* __restrict__ times,
                                              unsigned char* __restrict__ obs,
                                              unsigned* __restrict__ anyv,
                                              float* __restrict__ xd0) {
  const int b = blockIdx.x;
  const float* Xb = X + (size_t)b * T_SZ * C_CH;
  for (int t = threadIdx.x; t < T_SZ; t += 256) {
    const float* cur = Xb + t * C_CH;
    const float* prv = cur - C_CH;
    float m = -1e30f;
    if (t == 0) {
      #pragma unroll
      for (int c = 1; c <= 32; ++c) m = fmaxf(m, cur[c]);
    } else {
      #pragma unroll
      for (int c = 1; c <= 32; ++c) m = fmaxf(m, cur[c] - prv[c]);
    }
    unsigned char o = (m > 0.5f) ? (unsigned char)1 : (unsigned char)0;
    obs[(size_t)b * T_SZ + t] = o;
    if (o) atomicOr(&anyv[t], 1u);
    xd0[(size_t)b * T_SZ + t] = cur[0] - times[(t == 0) ? 0 : (t - 1)];
  }
}

// ---------------- phase 1b: per-element dt prefix + flag table -----------
// One block (1 wave) per batch element: coalesced loads, in-lane prefix of 8
// + wave __shfl_up scan. S[t][b] = {dt_used(b,t), flag = any && obs && t<=fi}
__global__ __launch_bounds__(64) void k_dt(const unsigned char* __restrict__ obs,
                                           const unsigned* __restrict__ anyv,
                                           const float* __restrict__ xd0,
                                           const int* __restrict__ fidx,
                                           float2* __restrict__ S) {
  const int b = blockIdx.x;
  const int lane = threadIdx.x;
  const int t0 = lane * 8;
  const unsigned long long o8 =
      *(const unsigned long long*)(obs + (size_t)b * T_SZ + t0);
  const float4* xd4 = (const float4*)(xd0 + (size_t)b * T_SZ + t0);
  const float4 xa = xd4[0], xb = xd4[1];
  const uint4* av4 = (const uint4*)(anyv + t0);
  const uint4 aa = av4[0], ab = av4[1];
  const int fi = fidx[b];
  const float xv[8] = {xa.x, xa.y, xa.z, xa.w, xb.x, xb.y, xb.z, xb.w};
  const unsigned av[8] = {aa.x, aa.y, aa.z, aa.w, ab.x, ab.y, ab.z, ab.w};
  float run = 0.f;
  float dtl[8], fl[8];
  #pragma unroll
  for (int j = 0; j < 8; ++j) {
    const int o = (int)((o8 >> (8 * j)) & 0xffULL);
    const int any = (int)av[j];
    dtl[j] = run;
    if (any && !o) run += xv[j];
    fl[j] = (any && o && (t0 + j) <= fi) ? 1.f : 0.f;
  }
  // wave-exclusive scan of per-lane totals
  float inc = run;
  #pragma unroll
  for (int off = 1; off < 64; off <<= 1) {
    float u = __shfl_up(inc, off, 64);
    if (lane >= off) inc += u;
  }
  const float excl = inc - run;
  #pragma unroll
  for (int j = 0; j < 8; ++j)
    S[(size_t)(t0 + j) * B_SZ + b] = make_float2(excl + dtl[j], fl[j]);
}

// ---------------- phase 1c: pack PRESCALED weights into bf16 B-frags -----
__global__ __launch_bounds__(256) void k_pack(const float* __restrict__ w_ih,
                                              const float* __restrict__ w_hh,
                                              unsigned short* __restrict__ whh_f,
                                              unsigned short* __restrict__ wih_f) {
  int i = blockIdx.x * 256 + threadIdx.x;
  if (i < 9600) {
    int l = i & 63; int kt = (i >> 6) % 5; int g = (i / 320) % 3; int q = i / 960;
    const float scl = (g < 2) ? -LOG2E : -2.f * LOG2E;
    int row = g * 160 + q * 16 + (l & 15);
    const float* src = w_hh + (size_t)row * HID + kt * 32 + (l >> 4) * 8;
    unsigned short* dst = whh_f + (size_t)i * 8;
    #pragma unroll
    for (int j = 0; j < 8; ++j) dst[j] = f2bf(scl * src[j]);
  } else if (i < 11520) {
    int i2 = i - 9600;
    int l = i2 & 63; int g = (i2 >> 6) % 3; int q = i2 / 192;
    const float scl = (g < 2) ? -LOG2E : -2.f * LOG2E;
    int row = g * 160 + q * 16 + (l & 15);
    const float* src = w_ih + (size_t)row * 32 + (l >> 4) * 8;
    unsigned short* dst = wih_f + (size_t)i2 * 8;
    #pragma unroll
    for (int j = 0; j < 8; ++j) dst[j] = f2bf(scl * src[j]);
  }
}

#define MFMA16 __builtin_amdgcn_mfma_f32_16x16x32_bf16

// ---------------- phase 2: batched MFMA recurrence ------------------------
// Loop order per step: barrier -> ds_read h (issue) -> gin MFMAs (cover LDS
// latency) -> prefetch t+1 -> 15 hh MFMAs -> packed-f32x2 combine -> write.
// S-dependent FMAs hoisted to the prefetch of the PREVIOUS step.
__global__ __launch_bounds__(NTHR) void k_scan(
    const float* __restrict__ X, const int* __restrict__ fidx,
    const float* __restrict__ w_ih,
    const float* __restrict__ b_ih, const float* __restrict__ b_hh,
    const float* __restrict__ lin_w, const float* __restrict__ lin_b,
    const float2* __restrict__ Sf,
    const unsigned short* __restrict__ whh_f, const unsigned short* __restrict__ wih_f,
    float* __restrict__ out)
{
  const int b0 = blockIdx.x * M_ELEM;
  const int tid = threadIdx.x;
  const int wid = tid >> 6;
  const int lane = tid & 63;
  const int q = wid;

  __shared__ __align__(16) unsigned short hrow[2][M_ELEM][HPAD]; // bf16 h dbuf
  __shared__ __align__(16) float hm[M_ELEM][HID];

  { unsigned int* hz = (unsigned int*)hrow;
    for (int i = tid; i < 2 * M_ELEM * HPAD / 2; i += NTHR) hz[i] = 0u; }

  int maxfi = 0;
  #pragma unroll
  for (int e = 0; e < M_ELEM; ++e) maxfi = max(maxfi, fidx[b0 + e]);

  // A-frag row -> element map (rows 8-15 permuted duplicates)
  const int r16 = lane & 15;
  const int elA = (r16 < 8) ? r16 : ((r16 & 4) | ((r16 & 3) ^ 2));
  // combine rows: always acc regs {0,1}
  const int mA = ((lane >> 4) & 1) * 4 + ((lane >> 5) & 1) * 2;
  const int mB = mA + 1;

  // ---- resident weight fragments ----
  bf16x8_t whh_v[3][5];
  bf16x8_t wih_v[3];
  #pragma unroll
  for (int g = 0; g < 3; ++g) {
    #pragma unroll
    for (int kt = 0; kt < 5; ++kt)
      whh_v[g][kt] = *(const bf16x8_t*)(whh_f + ((size_t)((q * 3 + g) * 5 + kt) * 64 + lane) * 8);
    wih_v[g] = *(const bf16x8_t*)(wih_f + ((size_t)(q * 3 + g) * 64 + lane) * 8);
  }
  const int col = q * 16 + (lane & 15);
  const float b_r  = -LOG2E * (b_ih[col] + b_hh[col]);
  const float b_z  = -LOG2E * (b_ih[160 + col] + b_hh[160 + col]);
  const float b_ni = -2.f * LOG2E * b_ih[320 + col];
  const float b_nh = -2.f * LOG2E * b_hh[320 + col];
  const float w0r = -LOG2E * w_ih[(size_t)col * 32];
  const float w0z = -LOG2E * w_ih[(size_t)(160 + col) * 32];
  const float w0n = -2.f * LOG2E * w_ih[(size_t)(320 + col) * 32];
  const f32x2_t bnh2 = {b_nh, b_nh};

  f32x2_t h2 = {0.f, 0.f};
  const f32x4_t z4 = {0.f, 0.f, 0.f, 0.f};

  const float* xrow_base =
      X + ((size_t)(b0 + elA) * T_SZ) * C_CH + 33 + ((lane >> 4) * 8);

  // ---- prologue: x(0) into regs, S(0) -> combine constants ----
  float xc[8];
  #pragma unroll
  for (int j = 0; j < 8; ++j) xc[j] = xrow_base[j];
  f32x2_t cr, cz, cn, fl2;
  {
    const float2 sA = Sf[b0 + mA];
    const float2 sB = Sf[b0 + mB];
    cr = (f32x2_t){fmaf(sA.x, w0r, b_r), fmaf(sB.x, w0r, b_r)};
    cz = (f32x2_t){fmaf(sA.x, w0z, b_z), fmaf(sB.x, w0z, b_z)};
    cn = (f32x2_t){fmaf(sA.x, w0n, b_ni), fmaf(sB.x, w0n, b_ni)};
    fl2 = (f32x2_t){sA.y, sB.y};
  }
  __syncthreads();

  // ---- the recurrence ----
  for (int t = 0; t <= maxfi; ++t) {
    const int p = t & 1, pn = p ^ 1;
    const int tn = (t < maxfi) ? (t + 1) : maxfi;

    // 1. h A-frags: issue 5x ds_read_b128 (latency covered by gin MFMAs)
    bf16x8_t hf0, hf1, hf2, hf3, hf4;
    {
      const unsigned short* hp = &hrow[p][elA][(lane >> 4) * 8];
      hf0 = *(const bf16x8_t*)(hp);
      hf1 = *(const bf16x8_t*)(hp + 32);
      hf2 = *(const bf16x8_t*)(hp + 64);
      hf3 = *(const bf16x8_t*)(hp + 96);
      hf4 = *(const bf16x8_t*)(hp + 128);
    }

    // 2. gin = x(t) @ W_ih^T (independent of h; covers ds_read latency)
    bf16x8_t xf; unsigned* xfu = (unsigned*)&xf;
    #pragma unroll
    for (int j = 0; j < 4; ++j) xfu[j] = cvt_pk_bf16(xc[2 * j], xc[2 * j + 1]);
    f32x4_t ginr = MFMA16(xf, wih_v[0], z4, 0, 0, 0);
    f32x4_t ginz = MFMA16(xf, wih_v[1], z4, 0, 0, 0);
    f32x4_t ginn = MFMA16(xf, wih_v[2], z4, 0, 0, 0);

    // 3. prefetch t+1 (x row + S entries)
    float xn[8];
    const float* xr = xrow_base + (size_t)tn * C_CH;
    #pragma unroll
    for (int j = 0; j < 8; ++j) xn[j] = xr[j];
    const float2 sAn = Sf[(size_t)tn * B_SZ + b0 + mA];
    const float2 sBn = Sf[(size_t)tn * B_SZ + b0 + mB];

    // 4. 15 hh MFMAs, gin as C-input, 6 parallel chains
    __builtin_amdgcn_s_setprio(1);
    f32x4_t ra  = MFMA16(hf0, whh_v[0][0], ginr, 0, 0, 0);
    f32x4_t za  = MFMA16(hf0, whh_v[1][0], ginz, 0, 0, 0);
    f32x4_t nha = MFMA16(hf0, whh_v[2][0], z4,   0, 0, 0);
    f32x4_t rb  = MFMA16(hf2, whh_v[0][2], z4,   0, 0, 0);
    f32x4_t zb  = MFMA16(hf2, whh_v[1][2], z4,   0, 0, 0);
    f32x4_t nhb = MFMA16(hf3, whh_v[2][3], z4,   0, 0, 0);
    ra  = MFMA16(hf1, whh_v[0][1], ra,  0, 0, 0);
    za  = MFMA16(hf1, whh_v[1][1], za,  0, 0, 0);
    nha = MFMA16(hf1, whh_v[2][1], nha, 0, 0, 0);
    rb  = MFMA16(hf3, whh_v[0][3], rb,  0, 0, 0);
    zb  = MFMA16(hf3, whh_v[1][3], zb,  0, 0, 0);
    nhb = MFMA16(hf4, whh_v[2][4], nhb, 0, 0, 0);
    nha = MFMA16(hf2, whh_v[2][2], nha, 0, 0, 0);
    rb  = MFMA16(hf4, whh_v[0][4], rb,  0, 0, 0);
    zb  = MFMA16(hf4, whh_v[1][4], zb,  0, 0, 0);
    __builtin_amdgcn_s_setprio(0);

    // 5. packed combine: only acc components [0:1] are real rows (mA,mB)
    {
      const f32x2_t pr = lo2(ra) + lo2(rb) + cr;
      const f32x2_t pz = lo2(za) + lo2(zb) + cz;
      const f32x2_t ph = lo2(nha) + lo2(nhb) + bnh2;
      const f32x2_t pni = lo2(ginn) + cn;
      const f32x2_t rr = {rcp_f(1.f + exp2_f(pr.x)), rcp_f(1.f + exp2_f(pr.y))};
      const f32x2_t zz = {rcp_f(1.f + exp2_f(pz.x)), rcp_f(1.f + exp2_f(pz.y))};
      f32x2_t u = pni + rr * ph;
      u.x = fminf(u.x, 60.f); u.y = fminf(u.y, 60.f);
      const f32x2_t e = {exp2_f(u.x), exp2_f(u.y)};
      const f32x2_t nn = ((f32x2_t){1.f, 1.f} - e) *
                         (f32x2_t){rcp_f(1.f + e.x), rcp_f(1.f + e.y)};
      const f32x2_t upd = nn + zz * (h2 - nn);
      h2 = h2 + fl2 * (upd - h2);
    }

    // 6. publish h (2x ds_write_b16); roll prefetched state
    {
      const unsigned hw = cvt_pk_bf16(h2.x, h2.y);
      hrow[pn][mA][col] = (unsigned short)hw;
      hrow[pn][mB][col] = (unsigned short)(hw >> 16);
    }
    cr = (f32x2_t){fmaf(sAn.x, w0r, b_r), fmaf(sBn.x, w0r, b_r)};
    cz = (f32x2_t){fmaf(sAn.x, w0z, b_z), fmaf(sBn.x, w0z, b_z)};
    cn = (f32x2_t){fmaf(sAn.x, w0n, b_ni), fmaf(sBn.x, w0n, b_ni)};
    fl2 = (f32x2_t){sAn.y, sBn.y};
    #pragma unroll
    for (int j = 0; j < 8; ++j) xc[j] = xn[j];
    __syncthreads();
  }

  // ---- epilogue: h -> LDS, then out = lin_w @ h + lin_b ----
  hm[mA][col] = h2.x;
  hm[mB][col] = h2.y;
  __syncthreads();
  if (tid < 256) {
    const int e = tid >> 5, o = tid & 31;
    const float4* lw = (const float4*)(lin_w + o * HID);
    const float4* hv = (const float4*)(&hm[e][0]);
    float a0 = 0.f, a1 = 0.f, a2 = 0.f, a3 = 0.f;
    #pragma unroll
    for (int k = 0; k < HID / 4; ++k) {
      float4 w = lw[k], h = hv[k];
      a0 = fmaf(w.x, h.x, a0); a1 = fmaf(w.y, h.y, a1);
      a2 = fmaf(w.z, h.z, a2); a3 = fmaf(w.w, h.w, a3);
    }
    out[(size_t)(b0 + e) * OUTD + o] = lin_b[o] + (a0 + a1) + (a2 + a3);
  }
}

extern "C" void kernel_launch(void* const* d_in, const int* in_sizes, int n_in,
                              void* d_out, int out_size, void* d_ws, size_t ws_size,
                              hipStream_t stream) {
  const float* times = (const float*)d_in[0];
  const float* X     = (const float*)d_in[1];
  const int*   fidx  = (const int*)d_in[2];
  const float* w_ih  = (const float*)d_in[3];
  const float* w_hh  = (const float*)d_in[4];
  const float* b_ih  = (const float*)d_in[5];
  const float* b_hh  = (const float*)d_in[6];
  const float* lin_w = (const float*)d_in[7];
  const float* lin_b = (const float*)d_in[8];
  float* outp = (float*)d_out;

  unsigned char* obsb = (unsigned char*)d_ws + OBS_OFF;
  unsigned* anyv = (unsigned*)((char*)d_ws + ANY_OFF);
  float* xd0 = (float*)((char*)d_ws + XD0_OFF);
  float2* S = (float2*)((char*)d_ws + S_OFF);
  unsigned short* whh_f = (unsigned short*)((char*)d_ws + WHH_OFF);
  unsigned short* wih_f = (unsigned short*)((char*)d_ws + WIH_OFF);

  k_zero<<<1, 512, 0, stream>>>(anyv);
  k_prep<<<B_SZ, 256, 0, stream>>>(X, times, obsb, anyv, xd0);
  k_dt<<<B_SZ, 64, 0, stream>>>(obsb, anyv, xd0, fidx, S);
  k_pack<<<45, 256, 0, stream>>>(w_ih, w_hh, whh_f, wih_f);
  k_scan<<<NBLK, NTHR, 0, stream>>>(X, fidx, w_ih, b_ih, b_hh,
                                    lin_w, lin_b, S, whh_f, wih_f, outp);
}